// Round 1
// baseline (71.470 us; speedup 1.0000x reference)
//
#include <hip/hip_runtime.h>
#include <math.h>

#define BB 8
#define LL 8192
#define CC 512

#define H0_OFF (BB*CC)            // 4096
#define A_OFF  (H0_OFF + BB*CC*4) // 20480

#define F_ALPHA_BASE 1.2f
#define F_ALPHA_SCALE 0.3f
#define F_GRAPH_LAMBDA 0.3f
#define F_FUSION_BETA 0.1f
#define F_PRIOR_BETA 0.2f
#define F_LN_EPS 1e-5f

// ---------------- Kernel 1: partial stats over L ----------------
// grid = BB * nchunkb, block = 256. Each block: 128-row slab (two 64-row halves),
// float4 per lane over columns. Partials layout: [b][chunk][3][C], chunk = cb*2+sub.
__global__ __launch_bounds__(256) void k_stats(const float* __restrict__ res,
                                               float* __restrict__ pbuf,
                                               int nchunkb) {
    int b = blockIdx.x / nchunkb;
    int cb = blockIdx.x % nchunkb;
    int rows_pb = LL / nchunkb;      // rows per block
    int half = rows_pb >> 1;
    int sub = threadIdx.x >> 7;      // 0/1
    int c4 = (threadIdx.x & 127) * 4;
    int r0 = cb * rows_pb + sub * half;
    const float* base = res + ((size_t)b * LL + r0) * CC + c4;

    float s0 = 0.f, s1 = 0.f, s2 = 0.f, s3 = 0.f;
    float m0 = 0.f, m1 = 0.f, m2 = 0.f, m3 = 0.f;
    float q0 = 0.f, q1 = 0.f, q2 = 0.f, q3 = 0.f;
    #pragma unroll 4
    for (int r = 0; r < half; r++) {
        float4 v = *(const float4*)(base + (size_t)r * CC);
        s0 += fabsf(v.x); s1 += fabsf(v.y); s2 += fabsf(v.z); s3 += fabsf(v.w);
        m0 = fmaxf(m0, fabsf(v.x)); m1 = fmaxf(m1, fabsf(v.y));
        m2 = fmaxf(m2, fabsf(v.z)); m3 = fmaxf(m3, fabsf(v.w));
        q0 = fmaf(v.x, v.x, q0); q1 = fmaf(v.y, v.y, q1);
        q2 = fmaf(v.z, v.z, q2); q3 = fmaf(v.w, v.w, q3);
    }
    int nchunk = 2 * nchunkb;
    int chunk = cb * 2 + sub;
    float* pb = pbuf + (size_t)((b * nchunk + chunk) * 3) * CC + c4;
    *(float4*)(pb)          = make_float4(s0, s1, s2, s3);
    *(float4*)(pb + CC)     = make_float4(m0, m1, m2, m3);
    *(float4*)(pb + 2 * CC) = make_float4(q0, q1, q2, q3);
}

// ---------------- Kernel 2: prior = relu(ne @ ne^T) ----------------
__global__ __launch_bounds__(256) void k_prior(const float* __restrict__ ne,
                                               float* __restrict__ prior) {
    int idx = blockIdx.x * 256 + threadIdx.x;  // c*512 + d
    int c = idx >> 9;
    int d = idx & 511;
    float s = 0.f;
    #pragma unroll
    for (int t = 0; t < 16; t++) s = fmaf(ne[c * 16 + t], ne[d * 16 + t], s);
    prior[idx] = fmaxf(s, 0.f);
}

// ---------------- Kernel 3: finish reduction -> h0 ----------------
__global__ __launch_bounds__(64) void k_h0(const float* __restrict__ pbuf,
                                           int nchunk,
                                           float* __restrict__ out) {
    int g = blockIdx.x * 64 + threadIdx.x;  // b*C + c
    int b = g >> 9;
    int c = g & 511;
    float sum = 0.f, mx = 0.f, sq = 0.f;
    const float* p = pbuf + (size_t)(b * nchunk * 3) * CC + c;
    #pragma unroll 4
    for (int ch = 0; ch < nchunk; ch++) {
        sum += p[0];
        mx = fmaxf(mx, p[CC]);
        sq += p[2 * CC];
        p += 3 * CC;
    }
    float m = sum * (1.f / LL);
    float sqm = sq * (1.f / LL);
    float sd = sqrtf(fmaxf(sqm - m * m, 0.f));
    *(float4*)(out + H0_OFF + (size_t)g * 4) = make_float4(m, mx, sd, sqm);
}

// ---------------- Kernel 4: rows — adjacency softmax + msg + head ----------------
// grid = BB * (CC/4), block 256 (4 waves, one row each).
__global__ __launch_bounds__(256) void k_rows(
    const float* __restrict__ h0,   // out + H0_OFF, [B][C][4]
    const float* __restrict__ prior,
    const float* __restrict__ Wl1, const float* __restrict__ bl1,
    const float* __restrict__ Wl2, const float* __restrict__ bl2,
    const float* __restrict__ Wg,  const float* __restrict__ bg,
    const float* __restrict__ Wq,  const float* __restrict__ bq,
    const float* __restrict__ Wk,  const float* __restrict__ bk,
    const float* __restrict__ Wf,  const float* __restrict__ bf,
    const float* __restrict__ Wo,  const float* __restrict__ bo,
    const float* __restrict__ lng, const float* __restrict__ lnb,
    float* __restrict__ out) {
    // transposed pair layout: [t2][col] of float2 -> consecutive-lane reads 2-way bank (free)
    __shared__ float kls[8 * CC * 2];    // 32 KB
    __shared__ float hgls[8 * CC * 2];   // 32 KB
    int b = blockIdx.x >> 7;
    int rb = blockIdx.x & 127;

    // stage: each thread computes k/h_graph_in projections for 2 columns
    #pragma unroll
    for (int ccy = 0; ccy < 2; ccy++) {
        int col = threadIdx.x * 2 + ccy;
        float4 hv = *(const float4*)(h0 + ((size_t)b * CC + col) * 4);
        float s[4] = {hv.x, hv.y, hv.z, hv.w};
        #pragma unroll
        for (int t2 = 0; t2 < 8; t2++) {
            float k0 = bk[2 * t2], k1 = bk[2 * t2 + 1];
            float g0 = bg[2 * t2], g1 = bg[2 * t2 + 1];
            #pragma unroll
            for (int j = 0; j < 4; j++) {
                k0 = fmaf(Wk[(2 * t2) * 4 + j], s[j], k0);
                k1 = fmaf(Wk[(2 * t2 + 1) * 4 + j], s[j], k1);
                g0 = fmaf(Wg[(2 * t2) * 4 + j], s[j], g0);
                g1 = fmaf(Wg[(2 * t2 + 1) * 4 + j], s[j], g1);
            }
            *(float2*)&kls[(t2 * CC + col) * 2] = make_float2(k0, k1);
            *(float2*)&hgls[(t2 * CC + col) * 2] = make_float2(g0, g1);
        }
    }
    __syncthreads();

    int wid = threadIdx.x >> 6;
    int lane = threadIdx.x & 63;
    int row = rb * 4 + wid;

    float4 hr = *(const float4*)(h0 + ((size_t)b * CC + row) * 4);
    float s[4] = {hr.x, hr.y, hr.z, hr.w};
    float qr[16];
    #pragma unroll
    for (int i = 0; i < 16; i++) {
        float a = bq[i];
        #pragma unroll
        for (int j = 0; j < 4; j++) a = fmaf(Wq[i * 4 + j], s[j], a);
        qr[i] = a;
    }

    const float* prow = prior + (size_t)row * CC;
    float sv[8];
    float mxv = -1e30f;
    #pragma unroll
    for (int j = 0; j < 8; j++) {
        int col = lane + 64 * j;
        float acc = 0.f;
        #pragma unroll
        for (int t2 = 0; t2 < 8; t2++) {
            float2 kk = *(const float2*)&kls[(t2 * CC + col) * 2];
            acc = fmaf(qr[2 * t2], kk.x, acc);
            acc = fmaf(qr[2 * t2 + 1], kk.y, acc);
        }
        float sim = fmaxf(acc, 0.f) + F_PRIOR_BETA * prow[col] + (col == row ? 1.f : 0.f);
        sv[j] = sim;
        mxv = fmaxf(mxv, sim);
    }
    #pragma unroll
    for (int o = 32; o; o >>= 1) mxv = fmaxf(mxv, __shfl_xor(mxv, o));

    float p[8], lsum = 0.f;
    float msg[16];
    #pragma unroll
    for (int h = 0; h < 16; h++) msg[h] = 0.f;
    #pragma unroll
    for (int j = 0; j < 8; j++) {
        int col = lane + 64 * j;
        float e = expf(sv[j] - mxv);
        p[j] = e;
        lsum += e;
        #pragma unroll
        for (int t2 = 0; t2 < 8; t2++) {
            float2 hh = *(const float2*)&hgls[(t2 * CC + col) * 2];
            msg[2 * t2]     = fmaf(e, hh.x, msg[2 * t2]);
            msg[2 * t2 + 1] = fmaf(e, hh.y, msg[2 * t2 + 1]);
        }
    }
    #pragma unroll
    for (int o = 32; o; o >>= 1) lsum += __shfl_xor(lsum, o);
    float inv = 1.f / lsum;

    // A row (coalesced)
    float* arow = out + A_OFF + ((size_t)b * CC + row) * CC;
    #pragma unroll
    for (int j = 0; j < 8; j++) arow[lane + 64 * j] = p[j] * inv;

    // full wave reduction of msg
    #pragma unroll
    for (int h = 0; h < 16; h++) {
        float v = msg[h];
        #pragma unroll
        for (int o = 32; o; o >>= 1) v += __shfl_xor(v, o);
        msg[h] = v * inv;
    }

    // ---- epilogue (redundant per lane; tiny) ----
    float t1[16];
    #pragma unroll
    for (int i = 0; i < 16; i++) {
        float a = bl1[i];
        #pragma unroll
        for (int j = 0; j < 4; j++) a = fmaf(Wl1[i * 4 + j], s[j], a);
        t1[i] = fmaxf(a, 0.f);
    }
    float hvec[16];
    float mu = 0.f;
    #pragma unroll
    for (int h = 0; h < 16; h++) {
        float hl = bl2[h];
        #pragma unroll
        for (int j = 0; j < 16; j++) hl = fmaf(Wl2[h * 16 + j], t1[j], hl);
        float hgr = hgls[((h >> 1) * CC + row) * 2 + (h & 1)];
        float hg2 = hgr + F_GRAPH_LAMBDA * fmaxf(msg[h], 0.f);
        float hv = hl + F_FUSION_BETA * hg2;
        hvec[h] = hv;
        mu += hv;
    }
    mu *= (1.f / 16.f);
    float var = 0.f;
    #pragma unroll
    for (int h = 0; h < 16; h++) { float d = hvec[h] - mu; var = fmaf(d, d, var); }
    var *= (1.f / 16.f);
    float istd = 1.f / sqrtf(var + F_LN_EPS);
    float hn[16];
    #pragma unroll
    for (int h = 0; h < 16; h++) hn[h] = (hvec[h] - mu) * istd * lng[h] + lnb[h];

    float acc2 = bo[0];
    #pragma unroll
    for (int o = 0; o < 16; o++) {
        float f = bf[o];
        #pragma unroll
        for (int t = 0; t < 16; t++) f = fmaf(Wf[o * 16 + t], hn[t], f);
        acc2 = fmaf(Wo[o], fmaxf(f, 0.f), acc2);
    }
    float alpha = F_ALPHA_BASE + F_ALPHA_SCALE * tanhf(acc2);
    if (lane == 0) out[(size_t)b * CC + row] = alpha;
}

extern "C" void kernel_launch(void* const* d_in, const int* in_sizes, int n_in,
                              void* d_out, int out_size, void* d_ws, size_t ws_size,
                              hipStream_t stream) {
    const float* res = (const float*)d_in[0];
    const float* ne  = (const float*)d_in[1];
    const float* Wl1 = (const float*)d_in[2];
    const float* bl1 = (const float*)d_in[3];
    const float* Wl2 = (const float*)d_in[4];
    const float* bl2 = (const float*)d_in[5];
    const float* Wg  = (const float*)d_in[6];
    const float* bg  = (const float*)d_in[7];
    const float* Wq  = (const float*)d_in[8];
    const float* bq  = (const float*)d_in[9];
    const float* Wk  = (const float*)d_in[10];
    const float* bk  = (const float*)d_in[11];
    const float* Wf  = (const float*)d_in[12];
    const float* bf  = (const float*)d_in[13];
    const float* Wo  = (const float*)d_in[14];
    const float* bo  = (const float*)d_in[15];
    const float* lng = (const float*)d_in[16];
    const float* lnb = (const float*)d_in[17];
    float* out = (float*)d_out;
    float* ws  = (float*)d_ws;

    // pick partial-chunk count to fit workspace: pbuf [B][2*nchunkb][3][C] + prior [C][C]
    int nchunkb = 64;
    while (nchunkb > 4) {
        size_t need = ((size_t)BB * (2 * nchunkb) * 3 * CC + (size_t)CC * CC) * sizeof(float);
        if (need <= ws_size) break;
        nchunkb >>= 1;
    }
    int nchunk = 2 * nchunkb;
    float* pbuf = ws;
    float* prior = ws + (size_t)BB * nchunk * 3 * CC;

    k_stats<<<BB * nchunkb, 256, 0, stream>>>(res, pbuf, nchunkb);
    k_prior<<<(CC * CC) / 256, 256, 0, stream>>>(ne, prior);
    k_h0<<<(BB * CC) / 64, 64, 0, stream>>>(pbuf, nchunk, out);
    k_rows<<<BB * (CC / 4), 256, 0, stream>>>(out + H0_OFF, prior,
                                              Wl1, bl1, Wl2, bl2, Wg, bg, Wq, bq, Wk, bk,
                                              Wf, bf, Wo, bo, lng, lnb, out);
}

// Round 2
// 55.978 us; speedup vs baseline: 1.2767x; 1.2767x over previous
//
#include <hip/hip_runtime.h>
#include <math.h>

#define BB 8
#define LL 8192
#define CC 512
#define NCHUNK 256   // stat chunks per b (one per k_stats block)

#define H0_OFF (BB*CC)            // 4096
#define A_OFF  (H0_OFF + BB*CC*4) // 20480

#define F_ALPHA_BASE 1.2f
#define F_ALPHA_SCALE 0.3f
#define F_GRAPH_LAMBDA 0.3f
#define F_FUSION_BETA 0.1f
#define F_PRIOR_BETA 0.2f
#define F_LN_EPS 1e-5f

// ---------------- Kernel 1: partial stats over L ----------------
// grid = BB*NCHUNK = 2048 blocks (8/CU, 32 waves/CU), block = 256.
// Each block: 32-row slab, each thread 2 columns (float2 = 8B/lane).
__global__ __launch_bounds__(256) void k_stats(const float* __restrict__ res,
                                               float* __restrict__ pbuf) {
    int b = blockIdx.x >> 8;
    int cb = blockIdx.x & 255;
    int c2 = threadIdx.x * 2;
    const float* base = res + ((size_t)b * LL + (size_t)cb * 32) * CC + c2;

    float s0 = 0.f, s1 = 0.f, m0 = 0.f, m1 = 0.f, q0 = 0.f, q1 = 0.f;
    #pragma unroll 8
    for (int r = 0; r < 32; r++) {
        float2 v = *(const float2*)(base + (size_t)r * CC);
        s0 += fabsf(v.x); s1 += fabsf(v.y);
        m0 = fmaxf(m0, fabsf(v.x)); m1 = fmaxf(m1, fabsf(v.y));
        q0 = fmaf(v.x, v.x, q0); q1 = fmaf(v.y, v.y, q1);
    }
    float* pb = pbuf + (size_t)((b * NCHUNK + cb) * 3) * CC + c2;
    *(float2*)(pb)          = make_float2(s0, s1);
    *(float2*)(pb + CC)     = make_float2(m0, m1);
    *(float2*)(pb + 2 * CC) = make_float2(q0, q1);
}

// ---------------- Kernel 2: fused h0-finish + prior ----------------
// blocks [0,64): h0 finish — 64 (b,c) pairs/block, 4 chunk-parts (one per wave),
//                LDS combine. blocks [64,1088): prior = relu(ne@ne^T).
__global__ __launch_bounds__(256) void k_mid(const float* __restrict__ pbuf,
                                             const float* __restrict__ ne,
                                             float* __restrict__ prior,
                                             float* __restrict__ out) {
    if (blockIdx.x < 64) {
        __shared__ float red[4][3][64];
        int lane = threadIdx.x & 63;
        int part = threadIdx.x >> 6;           // wave id 0..3
        int g = blockIdx.x * 64 + lane;        // b*C + c
        int b = g >> 9;
        int c = g & 511;
        float sum = 0.f, mx = 0.f, sq = 0.f;
        const float* p = pbuf + (size_t)((b * NCHUNK + part * 64) * 3) * CC + c;
        #pragma unroll 8
        for (int ch = 0; ch < 64; ch++) {
            sum += p[0];
            mx = fmaxf(mx, p[CC]);
            sq += p[2 * CC];
            p += 3 * CC;
        }
        red[part][0][lane] = sum;
        red[part][1][lane] = mx;
        red[part][2][lane] = sq;
        __syncthreads();
        if (threadIdx.x < 64) {
            float ts = red[0][0][lane] + red[1][0][lane] + red[2][0][lane] + red[3][0][lane];
            float tm = fmaxf(fmaxf(red[0][1][lane], red[1][1][lane]),
                             fmaxf(red[2][1][lane], red[3][1][lane]));
            float tq = red[0][2][lane] + red[1][2][lane] + red[2][2][lane] + red[3][2][lane];
            float m = ts * (1.f / LL);
            float sqm = tq * (1.f / LL);
            float sd = sqrtf(fmaxf(sqm - m * m, 0.f));
            *(float4*)(out + H0_OFF + (size_t)g * 4) = make_float4(m, tm, sd, sqm);
        }
    } else {
        int idx = (blockIdx.x - 64) * 256 + threadIdx.x;  // c*512 + d
        int c = idx >> 9;
        int d = idx & 511;
        float s = 0.f;
        #pragma unroll
        for (int t = 0; t < 16; t++) s = fmaf(ne[c * 16 + t], ne[d * 16 + t], s);
        prior[idx] = fmaxf(s, 0.f);
    }
}

// ---------------- Kernel 3: rows — adjacency softmax + msg + head ----------------
// grid = BB*(CC/8) = 512 blocks, block 256 (4 waves, TWO rows per wave).
__global__ __launch_bounds__(256) void k_rows(
    const float* __restrict__ h0,   // out + H0_OFF, [B][C][4]
    const float* __restrict__ prior,
    const float* __restrict__ Wl1, const float* __restrict__ bl1,
    const float* __restrict__ Wl2, const float* __restrict__ bl2,
    const float* __restrict__ Wg,  const float* __restrict__ bg,
    const float* __restrict__ Wq,  const float* __restrict__ bq,
    const float* __restrict__ Wk,  const float* __restrict__ bk,
    const float* __restrict__ Wf,  const float* __restrict__ bf,
    const float* __restrict__ Wo,  const float* __restrict__ bo,
    const float* __restrict__ lng, const float* __restrict__ lnb,
    float* __restrict__ out) {
    // [t2][col] float2 planes: stage writes at 8B lane stride (2-way = free),
    // main-loop reads at 8B lane stride (free).
    __shared__ float kls[8 * CC * 2];    // 32 KB
    __shared__ float hgls[8 * CC * 2];   // 32 KB
    int b = blockIdx.x >> 6;
    int rb = blockIdx.x & 63;

    // stage: each thread projects 2 columns (tid, tid+256) -> k, h_graph_in
    #pragma unroll
    for (int ccy = 0; ccy < 2; ccy++) {
        int col = threadIdx.x + ccy * 256;
        float4 hv = *(const float4*)(h0 + ((size_t)b * CC + col) * 4);
        float s[4] = {hv.x, hv.y, hv.z, hv.w};
        #pragma unroll
        for (int t2 = 0; t2 < 8; t2++) {
            float k0 = bk[2 * t2], k1 = bk[2 * t2 + 1];
            float g0 = bg[2 * t2], g1 = bg[2 * t2 + 1];
            #pragma unroll
            for (int j = 0; j < 4; j++) {
                k0 = fmaf(Wk[(2 * t2) * 4 + j], s[j], k0);
                k1 = fmaf(Wk[(2 * t2 + 1) * 4 + j], s[j], k1);
                g0 = fmaf(Wg[(2 * t2) * 4 + j], s[j], g0);
                g1 = fmaf(Wg[(2 * t2 + 1) * 4 + j], s[j], g1);
            }
            *(float2*)&kls[(t2 * CC + col) * 2] = make_float2(k0, k1);
            *(float2*)&hgls[(t2 * CC + col) * 2] = make_float2(g0, g1);
        }
    }
    __syncthreads();

    int wid = threadIdx.x >> 6;
    int lane = threadIdx.x & 63;
    int row0 = rb * 8 + wid * 2;   // this wave's two rows

    float s2[2][4];
    float qr[2][16];
    #pragma unroll
    for (int rr = 0; rr < 2; rr++) {
        float4 hr = *(const float4*)(h0 + ((size_t)b * CC + row0 + rr) * 4);
        s2[rr][0] = hr.x; s2[rr][1] = hr.y; s2[rr][2] = hr.z; s2[rr][3] = hr.w;
        #pragma unroll
        for (int i = 0; i < 16; i++) {
            float a = bq[i];
            #pragma unroll
            for (int j = 0; j < 4; j++) a = fmaf(Wq[i * 4 + j], s2[rr][j], a);
            qr[rr][i] = a;
        }
    }

    const float* prow0 = prior + (size_t)row0 * CC;
    float sv[2][8];
    float mx0 = -1e30f, mx1 = -1e30f;
    #pragma unroll
    for (int j = 0; j < 8; j++) {
        int col = lane + 64 * j;
        float a0 = 0.f, a1 = 0.f;
        #pragma unroll
        for (int t2 = 0; t2 < 8; t2++) {
            float2 kk = *(const float2*)&kls[(t2 * CC + col) * 2];
            a0 = fmaf(qr[0][2 * t2], kk.x, a0);
            a0 = fmaf(qr[0][2 * t2 + 1], kk.y, a0);
            a1 = fmaf(qr[1][2 * t2], kk.x, a1);
            a1 = fmaf(qr[1][2 * t2 + 1], kk.y, a1);
        }
        float p0 = prow0[col], p1 = prow0[CC + col];
        float v0 = fmaxf(a0, 0.f) + F_PRIOR_BETA * p0 + (col == row0 ? 1.f : 0.f);
        float v1 = fmaxf(a1, 0.f) + F_PRIOR_BETA * p1 + (col == row0 + 1 ? 1.f : 0.f);
        sv[0][j] = v0; sv[1][j] = v1;
        mx0 = fmaxf(mx0, v0); mx1 = fmaxf(mx1, v1);
    }
    #pragma unroll
    for (int o = 32; o; o >>= 1) {
        mx0 = fmaxf(mx0, __shfl_xor(mx0, o));
        mx1 = fmaxf(mx1, __shfl_xor(mx1, o));
    }

    float ls0 = 0.f, ls1 = 0.f;
    float msg[2][16];
    #pragma unroll
    for (int h = 0; h < 16; h++) { msg[0][h] = 0.f; msg[1][h] = 0.f; }
    #pragma unroll
    for (int j = 0; j < 8; j++) {
        int col = lane + 64 * j;
        float e0 = expf(sv[0][j] - mx0);
        float e1 = expf(sv[1][j] - mx1);
        sv[0][j] = e0; sv[1][j] = e1;
        ls0 += e0; ls1 += e1;
        #pragma unroll
        for (int t2 = 0; t2 < 8; t2++) {
            float2 hh = *(const float2*)&hgls[(t2 * CC + col) * 2];
            msg[0][2 * t2]     = fmaf(e0, hh.x, msg[0][2 * t2]);
            msg[0][2 * t2 + 1] = fmaf(e0, hh.y, msg[0][2 * t2 + 1]);
            msg[1][2 * t2]     = fmaf(e1, hh.x, msg[1][2 * t2]);
            msg[1][2 * t2 + 1] = fmaf(e1, hh.y, msg[1][2 * t2 + 1]);
        }
    }
    #pragma unroll
    for (int o = 32; o; o >>= 1) {
        ls0 += __shfl_xor(ls0, o);
        ls1 += __shfl_xor(ls1, o);
    }
    float inv0 = 1.f / ls0, inv1 = 1.f / ls1;

    // A rows (coalesced)
    float* arow0 = out + A_OFF + ((size_t)b * CC + row0) * CC;
    #pragma unroll
    for (int j = 0; j < 8; j++) {
        arow0[lane + 64 * j]      = sv[0][j] * inv0;
        arow0[CC + lane + 64 * j] = sv[1][j] * inv1;
    }

    // full wave reduction of msg
    #pragma unroll
    for (int h = 0; h < 16; h++) {
        float v0 = msg[0][h], v1 = msg[1][h];
        #pragma unroll
        for (int o = 32; o; o >>= 1) {
            v0 += __shfl_xor(v0, o);
            v1 += __shfl_xor(v1, o);
        }
        msg[0][h] = v0 * inv0;
        msg[1][h] = v1 * inv1;
    }

    // ---- epilogue (redundant per lane; tiny) ----
    #pragma unroll
    for (int rr = 0; rr < 2; rr++) {
        int row = row0 + rr;
        float t1[16];
        #pragma unroll
        for (int i = 0; i < 16; i++) {
            float a = bl1[i];
            #pragma unroll
            for (int j = 0; j < 4; j++) a = fmaf(Wl1[i * 4 + j], s2[rr][j], a);
            t1[i] = fmaxf(a, 0.f);
        }
        float hvec[16];
        float mu = 0.f;
        #pragma unroll
        for (int h = 0; h < 16; h++) {
            float hl = bl2[h];
            #pragma unroll
            for (int j = 0; j < 16; j++) hl = fmaf(Wl2[h * 16 + j], t1[j], hl);
            float hgr = hgls[((h >> 1) * CC + row) * 2 + (h & 1)];
            float hg2 = hgr + F_GRAPH_LAMBDA * fmaxf(msg[rr][h], 0.f);
            float hv = hl + F_FUSION_BETA * hg2;
            hvec[h] = hv;
            mu += hv;
        }
        mu *= (1.f / 16.f);
        float var = 0.f;
        #pragma unroll
        for (int h = 0; h < 16; h++) { float d = hvec[h] - mu; var = fmaf(d, d, var); }
        var *= (1.f / 16.f);
        float istd = 1.f / sqrtf(var + F_LN_EPS);
        float hn[16];
        #pragma unroll
        for (int h = 0; h < 16; h++) hn[h] = (hvec[h] - mu) * istd * lng[h] + lnb[h];

        float acc2 = bo[0];
        #pragma unroll
        for (int o = 0; o < 16; o++) {
            float f = bf[o];
            #pragma unroll
            for (int t = 0; t < 16; t++) f = fmaf(Wf[o * 16 + t], hn[t], f);
            acc2 = fmaf(Wo[o], fmaxf(f, 0.f), acc2);
        }
        float alpha = F_ALPHA_BASE + F_ALPHA_SCALE * tanhf(acc2);
        if (lane == 0) out[(size_t)b * CC + row] = alpha;
    }
}

extern "C" void kernel_launch(void* const* d_in, const int* in_sizes, int n_in,
                              void* d_out, int out_size, void* d_ws, size_t ws_size,
                              hipStream_t stream) {
    const float* res = (const float*)d_in[0];
    const float* ne  = (const float*)d_in[1];
    const float* Wl1 = (const float*)d_in[2];
    const float* bl1 = (const float*)d_in[3];
    const float* Wl2 = (const float*)d_in[4];
    const float* bl2 = (const float*)d_in[5];
    const float* Wg  = (const float*)d_in[6];
    const float* bg  = (const float*)d_in[7];
    const float* Wq  = (const float*)d_in[8];
    const float* bq  = (const float*)d_in[9];
    const float* Wk  = (const float*)d_in[10];
    const float* bk  = (const float*)d_in[11];
    const float* Wf  = (const float*)d_in[12];
    const float* bf  = (const float*)d_in[13];
    const float* Wo  = (const float*)d_in[14];
    const float* bo  = (const float*)d_in[15];
    const float* lng = (const float*)d_in[16];
    const float* lnb = (const float*)d_in[17];
    float* out = (float*)d_out;
    float* ws  = (float*)d_ws;

    float* pbuf = ws;                                          // [B][NCHUNK][3][C]
    float* prior = ws + (size_t)BB * NCHUNK * 3 * CC;          // [C][C]

    k_stats<<<BB * NCHUNK, 256, 0, stream>>>(res, pbuf);
    k_mid<<<64 + (CC * CC) / 256, 256, 0, stream>>>(pbuf, ne, prior, out);
    k_rows<<<BB * (CC / 8), 256, 0, stream>>>(out + H0_OFF, prior,
                                              Wl1, bl1, Wl2, bl2, Wg, bg, Wq, bq, Wk, bk,
                                              Wf, bf, Wo, bo, lng, lnb, out);
}